// Round 5
// baseline (215.329 us; speedup 1.0000x reference)
//
#include <hip/hip_runtime.h>

#define BB 2048
#define TT 2048
#define CC 8
#define AA 27
#define HH 8

typedef float floatx4 __attribute__((ext_vector_type(4)));  // native vec for nontemporal store

// ---------------- Kernel 1: per-sample MLP -> ws ----------------
// 2048 samples; block = 256 threads = 32 samples x 8 hidden-units.
__global__ __launch_bounds__(256) void mlp_kernel(
    const float* __restrict__ attrs,      // [B,A]
    const float* __restrict__ w1,         // [A,H]
    const float* __restrict__ b1,         // [H]
    const float* __restrict__ w2,         // [H,C]
    const float* __restrict__ b2,         // [C]
    const float* __restrict__ bw1,        // [A,H]
    const float* __restrict__ bb1,        // [H]
    const float* __restrict__ bw2,        // [H,1]
    const float* __restrict__ bb2,        // [1]
    const float* __restrict__ mask_attrs, // [B,A]
    const float* __restrict__ mask_hidden,// [B,H]
    float* __restrict__ ker,              // [B,C]  (ws)
    float* __restrict__ bias)             // [B]    (ws)
{
    const int tid = threadIdx.x;
    const int s   = tid >> 3;             // local sample 0..31
    const int h   = tid & 7;              // hidden unit / out channel
    const int b   = blockIdx.x * 32 + s;

    __shared__ float s_hw[32][HH];
    __shared__ float s_hb[32][HH];

    {
        float hw = b1[h];
        float hb = bb1[h];
        const float* ab = attrs      + b * AA;
        const float* mb = mask_attrs + b * AA;
        #pragma unroll
        for (int i = 0; i < AA; ++i) {
            const float a = ab[i] * mb[i];
            hw = fmaf(a, w1 [i * HH + h], hw);
            hb = fmaf(a, bw1[i * HH + h], hb);
        }
        const float mh = mask_hidden[b * HH + h];
        s_hw[s][h] = fmaxf(hw, 0.0f) * mh;
        s_hb[s][h] = fmaxf(hb, 0.0f) * mh;
    }
    __syncthreads();

    {
        const int c = h;
        float acc = b2[c];
        #pragma unroll
        for (int j = 0; j < HH; ++j)
            acc = fmaf(s_hw[s][j], w2[j * CC + c], acc);
        ker[b * CC + c] = tanhf(acc);
        if (c == 0) {
            float accb = bb2[0];
            #pragma unroll
            for (int j = 0; j < HH; ++j)
                accb = fmaf(s_hb[s][j], bw2[j], accb);
            bias[b] = tanhf(accb);
        }
    }
}

// ---------------- Kernel 2: streaming contraction, 4 outputs/thread ----------
// Each thread: 8 independent float4 loads (128 B contiguous), 4 dots,
// one nontemporal float4 store. Block covers 1024 consecutive t of one b.
__global__ __launch_bounds__(256) void stream_kernel(
    const float* __restrict__ x,          // [B,T,C]
    const float* __restrict__ ker,        // [B,C]
    const float* __restrict__ bias,       // [B]
    float* __restrict__ out)              // [B,T]
{
    const int b    = blockIdx.x >> 1;                         // 2 blocks per sample
    const int t0   = ((blockIdx.x & 1) << 10) + (threadIdx.x << 2);
    const size_t e = ((size_t)b << 11) + t0;                  // b*T + t0

    // 8 independent streaming loads (issue all before use)
    const float4* xp = reinterpret_cast<const float4*>(x + e * CC);
    float4 xv[8];
    #pragma unroll
    for (int i = 0; i < 8; ++i) xv[i] = xp[i];

    // hot broadcast loads (same address across the whole block -> L1)
    const float4* kp = reinterpret_cast<const float4*>(ker + b * CC);
    const float4 k0 = kp[0];
    const float4 k1 = kp[1];
    const float bs  = bias[b];

    floatx4 r;
    #pragma unroll
    for (int j = 0; j < 4; ++j) {
        float y = bs;
        const float4 a0 = xv[2 * j];
        const float4 a1 = xv[2 * j + 1];
        y = fmaf(a0.x, k0.x, y);
        y = fmaf(a0.y, k0.y, y);
        y = fmaf(a0.z, k0.z, y);
        y = fmaf(a0.w, k0.w, y);
        y = fmaf(a1.x, k1.x, y);
        y = fmaf(a1.y, k1.y, y);
        y = fmaf(a1.z, k1.z, y);
        y = fmaf(a1.w, k1.w, y);
        r[j] = (y > 0.0f) ? y : expm1f(y);   // ELU, alpha=1
    }
    __builtin_nontemporal_store(r, reinterpret_cast<floatx4*>(out + e));
}

extern "C" void kernel_launch(void* const* d_in, const int* in_sizes, int n_in,
                              void* d_out, int out_size, void* d_ws, size_t ws_size,
                              hipStream_t stream) {
    const float* x    = (const float*)d_in[0];
    const float* at   = (const float*)d_in[1];
    const float* w1   = (const float*)d_in[2];
    const float* b1   = (const float*)d_in[3];
    const float* w2   = (const float*)d_in[4];
    const float* b2   = (const float*)d_in[5];
    const float* bw1  = (const float*)d_in[6];
    const float* bb1  = (const float*)d_in[7];
    const float* bw2  = (const float*)d_in[8];
    const float* bb2  = (const float*)d_in[9];
    const float* ma   = (const float*)d_in[10];
    const float* mh   = (const float*)d_in[11];
    float* out = (float*)d_out;

    float* ker  = (float*)d_ws;                  // [B*C]  64 KB
    float* bias = (float*)d_ws + BB * CC;        // [B]     8 KB

    mlp_kernel<<<BB / 32, 256, 0, stream>>>(
        at, w1, b1, w2, b2, bw1, bb1, bw2, bb2, ma, mh, ker, bias);

    const int blocks = (BB * TT) / 1024;         // 4096 blocks, b uniform
    stream_kernel<<<blocks, 256, 0, stream>>>(x, ker, bias, out);
}